// Round 10
// baseline (302.731 us; speedup 1.0000x reference)
//
#include <hip/hip_runtime.h>
#include <math.h>

typedef _Float16 half8 __attribute__((ext_vector_type(8)));
typedef _Float16 half2v __attribute__((ext_vector_type(2)));
typedef __attribute__((ext_vector_type(4))) float f32x4;

// ---------------- workspace layout ----------------
#define US_XP    0
#define N_XP     (8*60*60*64)            // padded NHWC x, pad=2, fp16
#define US_WOFF  (US_XP + N_XP)          // offset-conv weights, 28 taps (25 real)
#define N_WOFF   (28*2*8*64*8)
#define US_W5    (US_WOFF + N_WOFF)      // w5 (25) + sub tap + 2 zero pads = 28
#define N_W5     (28*2*8*64*8)
#define US_W3    (US_W5 + N_W5)          // w3 (9) + sub tap + 2 zero pads = 12
#define N_W3     (12*2*8*64*8)
#define US_TOT   (US_W3 + N_W3)
#define FB_BYTES (((US_TOT*2) + 15) & ~15)
#define F_BOM    0                       // offset-conv bias (128, padded)
#define F_B5     128                     // b5 + sub_b
#define F_B3     256                     // b3 + sub_b
#define N_ITEMS  (8*34*3136)             // bilinear meta items (25 k5 + 9 k3)
#define F_OFFS   384                     // int4 per item (corner byte offsets)
#define F_WTS    (F_OFFS + N_ITEMS*4)    // uint2 per item (4 fp16 weights)

__device__ __forceinline__ unsigned short f2h(float f) {
    union { _Float16 h; unsigned short s; } c; c.h = (_Float16)f; return c.s;
}
__device__ __forceinline__ half2v splat_lo(unsigned u) {
    union { unsigned short s; _Float16 h; } c; c.s = (unsigned short)(u & 0xffffu);
    return (half2v){c.h, c.h};
}
__device__ __forceinline__ half2v splat_hi(unsigned u) {
    union { unsigned short s; _Float16 h; } c; c.s = (unsigned short)(u >> 16);
    return (half2v){c.h, c.h};
}
__device__ __forceinline__ unsigned blendh(unsigned a, unsigned b, unsigned c, unsigned d,
                                           half2v W00, half2v W01, half2v W10, half2v W11) {
    union { unsigned u; half2v h; } A, B, C, D, R;
    A.u = a; B.u = b; C.u = c; D.u = d;
    R.h = A.h*W00 + B.h*W01 + C.h*W10 + D.h*W11;   // v_pk_mul/fma_f16
    return R.u;
}

// ---------------- xpose: x NCHW fp32 -> padded NHWC fp16 + border zero ----------------
__global__ __launch_bounds__(256) void xpose(const float* __restrict__ x,
                                             unsigned short* __restrict__ xp)
{
    const int b = blockIdx.y;
    if (blockIdx.x == 49) {              // border zeroing (464 px per batch)
        const uint4 z = make_uint4(0,0,0,0);
        for (int i = threadIdx.x; i < 464*8; i += 256) {
            const int px = i >> 3, part = i & 7;
            int oy, ox;
            if (px < 120)      { oy = px/60;            ox = px%60; }
            else if (px < 240) { int j = px-120; oy = 58 + j/60; ox = j%60; }
            else               { int j = px-240; oy = 2 + (j>>2); ox = ((j&2)?58:0) + (j&1); }
            *(uint4*)(xp + ((size_t)b*3600 + oy*60 + ox)*64 + part*8) = z;
        }
        return;
    }
    __shared__ float ld[64*65];
    const int px0 = blockIdx.x * 64;
    const int t   = threadIdx.x;
#pragma unroll
    for (int c0 = 0; c0 < 64; c0 += 4) {
        const int c = c0 + (t >> 6);
        const int p = t & 63;
        ld[c*65 + p] = x[((size_t)(b*64 + c))*3136 + px0 + p];
    }
    __syncthreads();
    const int lp = t >> 2;
    const int ch0 = (t & 3) * 16;
    const int px = px0 + lp;
    const int oy = px/56, ox = px - oy*56;
    unsigned short* dst = xp + ((size_t)b*3600 + (oy+2)*60 + (ox+2))*64 + ch0;
    unsigned short tmp[16];
#pragma unroll
    for (int k = 0; k < 16; ++k) tmp[k] = f2h(ld[(ch0 + k)*65 + lp]);
    *(uint4*)dst       = *(uint4*)&tmp[0];
    *(uint4*)(dst + 8) = *(uint4*)&tmp[8];
}

// ---------------- prep_w: pack weights into A-frag order + biases (fp16) ----------------
// A-frag (16x16x32): lane l holds A[oc=l&15][c=(l>>4)*8+j]. idx ((((tap*2+kt)*8+oct)*64+lane)*8+j)
__global__ __launch_bounds__(256) void prep_w(
    const float* __restrict__ w3, const float* __restrict__ b3,
    const float* __restrict__ off3w, const float* __restrict__ off3b,
    const float* __restrict__ w5, const float* __restrict__ b5,
    const float* __restrict__ off5w, const float* __restrict__ off5b,
    const float* __restrict__ subw, const float* __restrict__ subb,
    unsigned short* __restrict__ us, float* __restrict__ fb)
{
    const int NTOT = US_TOT + 384;
    for (int i = US_WOFF + blockIdx.x*256 + threadIdx.x; i < NTOT; i += gridDim.x*256) {
        if (i < US_TOT) {
            float v = 0.f;
            int j, mode;
            if (i < US_W5)      { j = i - US_WOFF; mode = 0; }
            else if (i < US_W3) { j = i - US_W5;   mode = 1; }
            else                { j = i - US_W3;   mode = 2; }
            int j8   = j & 7;
            int lane = (j >> 3) & 63;
            int oct  = (j >> 9) & 7;
            int kt   = (j >> 12) & 1;
            int tap  = j >> 13;
            int oc   = oct*16 + (lane & 15);
            int c    = kt*32 + (lane >> 4)*8 + j8;
            if (mode == 0) {                    // offset conv (5x5, k3 embedded; taps 25..27 = 0)
                if (oc < 27 && tap < 25) {
                    int ky = tap/5, kx = tap%5;
                    if (ky>=1 && ky<=3 && kx>=1 && kx<=3)
                        v = off3w[((oc*64 + c)*3 + (ky-1))*3 + (kx-1)];
                } else if (oc >= 27 && oc < 102 && tap < 25) {
                    v = off5w[((oc-27)*64 + c)*25 + tap];
                }
            } else if (mode == 1) {             // w5 (25) + sub tap (25) + zeros (26,27)
                if (tap < 25)       v = w5[(oc*64 + c)*25 + tap];
                else if (tap == 25) v = subw[oc*64 + c];
            } else {                            // w3 (9) + sub tap (9) + zeros (10,11)
                if (tap < 9)        v = w3[(oc*64 + c)*9 + tap];
                else if (tap == 9)  v = subw[oc*64 + c];
            }
            us[i] = f2h(v);
        } else {
            int fj = i - US_TOT;
            float v;
            if (fj < 128)      v = (fj < 27) ? off3b[fj] : ((fj < 102) ? off5b[fj-27] : 0.f);
            else if (fj < 256) { int o = fj-128; v = b5[o] + subb[o]; }
            else               { int o = fj-256; v = b3[o] + subb[o]; }
            fb[fj] = v;
        }
    }
}

// ---------------- offset conv: 32 px x 128 oc, 4 taps/round (7 rounds), meta epilogue ----------
__global__ __launch_bounds__(256, 4) void convo6(
    const unsigned short* __restrict__ xp,
    const unsigned short* __restrict__ wp, const float* __restrict__ bias,
    int4* __restrict__ offs, uint2* __restrict__ wts)
{
    const int b    = blockIdx.y;
    const int pix0 = blockIdx.x * 32;
    const int lane = threadIdx.x & 63;
    const int wave = threadIdx.x >> 6;
    const int r15 = lane & 15, q4 = lane >> 4;
    const int cg  = lane & 7,  pr = lane >> 3;

    __shared__ __align__(16) unsigned short cols[2][4][32*72];   // 36864 B

    f32x4 acc[2][2] = {{{0.f,0.f,0.f,0.f},{0.f,0.f,0.f,0.f}},
                       {{0.f,0.f,0.f,0.f},{0.f,0.f,0.f,0.f}}};

    const char* xb = (const char*)(xp + (size_t)b*(60*60*64));
    const int px  = wave*8 + pr;
    const int pix = pix0 + px;
    const int oy  = pix/56, ox = pix - oy*56;
    const int coff = (((oy+2)*60) + ox + 2) << 7;

    uint4 G[4];
    auto issue = [&](int t0) {
#pragma unroll
        for (int j = 0; j < 4; ++j) {
            const int t = t0 + j;
            int k = 0;
            if (t < 25) { int ky = t/5, kx = t - ky*5; k = ((ky-2)*60 + (kx-2)) << 7; }
            G[j] = *(const uint4*)(xb + coff + k + cg*16);
        }
    };
    auto commit = [&](unsigned short (*buf)[32*72]) {
#pragma unroll
        for (int j = 0; j < 4; ++j)
            *(uint4*)&buf[j][px*72 + cg*8] = G[j];
    };
    auto gemm = [&](int tap, const unsigned short* buf) {
#pragma unroll
        for (int kt = 0; kt < 2; ++kt) {
            half8 A0 = *(const half8*)(wp + ((size_t)((tap*2+kt)*8 + wave*2    )*64 + lane)*8);
            half8 A1 = *(const half8*)(wp + ((size_t)((tap*2+kt)*8 + wave*2 + 1)*64 + lane)*8);
#pragma unroll
            for (int pt = 0; pt < 2; ++pt) {
                half8 Bf = *(const half8*)(buf + (pt*16 + r15)*72 + kt*32 + q4*8);
                acc[0][pt] = __builtin_amdgcn_mfma_f32_16x16x32_f16(A0, Bf, acc[0][pt], 0, 0, 0);
                acc[1][pt] = __builtin_amdgcn_mfma_f32_16x16x32_f16(A1, Bf, acc[1][pt], 0, 0, 0);
            }
        }
    };

    issue(0);
    commit(cols[0]);
    __syncthreads();
    for (int r = 0; r < 7; ++r) {
        if (r + 1 < 7) issue(4*r + 4);
#pragma unroll
        for (int tt = 0; tt < 4; ++tt) gemm(4*r + tt, cols[r&1][tt]);
        if (r + 1 < 7) commit(cols[(r+1)&1]);
        __syncthreads();
    }

    // ---- epilogue: om tile -> LDS (fp32 128x32), bilinear meta -> offs/wts ----
    float* omt = (float*)cols;
#pragma unroll
    for (int i = 0; i < 2; ++i)
#pragma unroll
    for (int pt = 0; pt < 2; ++pt)
#pragma unroll
    for (int reg = 0; reg < 4; ++reg) {
        const int oc = (wave*2 + i)*16 + q4*4 + reg;
        const int p2 = pt*16 + r15;
        omt[oc*32 + p2] = acc[i][pt][reg] + bias[oc];
    }
    __syncthreads();

    const int tid = threadIdx.x;
#pragma unroll
    for (int itr = 0; itr < 5; ++itr) {
        const int idx = itr*256 + tid;
        if (idx >= 34*32) break;
        const int t  = idx >> 5;
        const int p2 = idx & 31;
        const int pix2 = pix0 + p2;
        const int oy2 = pix2/56, ox2 = pix2 - oy2*56;
        int ky, kx, cdy, cdx, cml, HP, SH;
        if (t < 25) { ky = t/5; kx = t%5; cdy = 27+t; cdx = 52+t; cml = 77+t; HP = 60; SH = 0; }
        else { int tt = t-25; ky = tt/3; kx = tt%3; cdy = tt; cdx = 9+tt; cml = 18+tt; HP = 58; SH = 1; }
        const float dy = omt[cdy*32 + p2];
        const float dx = omt[cdx*32 + p2];
        const float ml = omt[cml*32 + p2];
        const float mask = 1.f / (1.f + __expf(-ml));
        const float py = (float)(oy2 + ky) + dy;
        const float qx = (float)(ox2 + kx) + dx;
        const float y0f = floorf(py), x0f = floorf(qx);
        const float ty = py - y0f, tx = qx - x0f;
        const int y0 = (int)y0f, x0 = (int)x0f, y1 = y0+1, x1 = x0+1;
        float w00 = (1.f-ty)*(1.f-tx)*mask;
        float w01 = (1.f-ty)*tx*mask;
        float w10 = ty*(1.f-tx)*mask;
        float w11 = ty*tx*mask;
        const bool vy0 = (unsigned)y0 < (unsigned)HP, vy1 = (unsigned)y1 < (unsigned)HP;
        const bool vx0 = (unsigned)x0 < (unsigned)HP, vx1 = (unsigned)x1 < (unsigned)HP;
        if (!(vy0 && vx0)) w00 = 0.f;
        if (!(vy0 && vx1)) w01 = 0.f;
        if (!(vy1 && vx0)) w10 = 0.f;
        if (!(vy1 && vx1)) w11 = 0.f;
        const int yc0 = min(max(y0,0),HP-1)+SH, yc1 = min(max(y1,0),HP-1)+SH;
        const int xc0 = min(max(x0,0),HP-1)+SH, xc1 = min(max(x1,0),HP-1)+SH;
        const int mi = (b*34 + t)*3136 + pix2;
        offs[mi] = make_int4((yc0*60+xc0)<<7, (yc0*60+xc1)<<7, (yc1*60+xc0)<<7, (yc1*60+xc1)<<7);
        wts[mi]  = make_uint2((unsigned)f2h(w00) | ((unsigned)f2h(w01) << 16),
                              (unsigned)f2h(w10) | ((unsigned)f2h(w11) << 16));
    }
}

// ---------------- deform conv: 32px x 128oc, 4 taps/round, pk_fma_f16 blend ----------
__global__ __launch_bounds__(256, 3) void convd6(
    const unsigned short* __restrict__ xp,
    const int4* __restrict__ offs, const uint2* __restrict__ wts,
    float* __restrict__ out,
    const unsigned short* __restrict__ wp5, const float* __restrict__ bias5,
    const unsigned short* __restrict__ wp3, const float* __restrict__ bias3)
{
    const int kind = blockIdx.z;                  // 0: k5 (first), 1: k3
    const unsigned short* wp = kind ? wp3 : wp5;
    const float* bias = kind ? bias3 : bias5;
    const int R     = kind ? 3  : 7;              // 4-tap rounds (12 / 28 taps)
    const int K2    = kind ? 9  : 25;
    const int tofs  = kind ? 25 : 0;
    const int outc0 = kind ? 0  : 128;

    const int b    = blockIdx.y;
    const int pix0 = blockIdx.x * 32;
    const int lane = threadIdx.x & 63;
    const int wave = threadIdx.x >> 6;
    const int r15 = lane & 15, q4 = lane >> 4;
    const int cg  = lane & 7,  pr = lane >> 3;

    __shared__ __align__(16) unsigned short cols[2][4][32*72];   // 36864 B

    f32x4 acc[2][2] = {{{0.f,0.f,0.f,0.f},{0.f,0.f,0.f,0.f}},
                       {{0.f,0.f,0.f,0.f},{0.f,0.f,0.f,0.f}}};

    const char* xb = (const char*)(xp + (size_t)b*(60*60*64));
    const int px  = wave*8 + pr;
    const int pix = pix0 + px;
    const int oy  = pix/56, ox = pix - oy*56;
    const int coff  = (((oy+2)*60) + ox + 2) << 7;
    const int mbase = (b*34 + tofs)*3136 + pix;

    uint4 C[4][4];                     // corners for 4 staged taps
    uint2 WC[4];
    int4  MOc[4], MOn[4];
    uint2 MWc[4], MWn[4];

    auto loadMetaN = [&](int t0) {
#pragma unroll
        for (int j = 0; j < 4; ++j) {
            const int a = min(t0 + j, K2-1) * 3136;
            MOn[j] = offs[mbase + a]; MWn[j] = wts[mbase + a];
        }
    };
    auto issue = [&](int t0) {
#pragma unroll
        for (int j = 0; j < 4; ++j) {
            const int t = t0 + j;
            if (t >= K2) {
                C[j][0] = *(const uint4*)(xb + coff + cg*16);
            } else {
                WC[j] = MWc[j];
                C[j][0] = *(const uint4*)(xb + MOc[j].x + cg*16);
                C[j][1] = *(const uint4*)(xb + MOc[j].y + cg*16);
                C[j][2] = *(const uint4*)(xb + MOc[j].z + cg*16);
                C[j][3] = *(const uint4*)(xb + MOc[j].w + cg*16);
            }
        }
    };
    auto commit = [&](int t0, unsigned short (*buf)[32*72]) {
#pragma unroll
        for (int j = 0; j < 4; ++j) {
            const int t = t0 + j;
            uint4 res;
            if (t >= K2) {
                res = C[j][0];
            } else {
                const half2v W00 = splat_lo(WC[j].x), W01 = splat_hi(WC[j].x);
                const half2v W10 = splat_lo(WC[j].y), W11 = splat_hi(WC[j].y);
                res.x = blendh(C[j][0].x, C[j][1].x, C[j][2].x, C[j][3].x, W00, W01, W10, W11);
                res.y = blendh(C[j][0].y, C[j][1].y, C[j][2].y, C[j][3].y, W00, W01, W10, W11);
                res.z = blendh(C[j][0].z, C[j][1].z, C[j][2].z, C[j][3].z, W00, W01, W10, W11);
                res.w = blendh(C[j][0].w, C[j][1].w, C[j][2].w, C[j][3].w, W00, W01, W10, W11);
            }
            *(uint4*)&buf[j][px*72 + cg*8] = res;
        }
    };
    auto gemm = [&](int tap, const unsigned short* buf) {
#pragma unroll
        for (int kt = 0; kt < 2; ++kt) {
            half8 A0 = *(const half8*)(wp + ((size_t)((tap*2+kt)*8 + wave*2    )*64 + lane)*8);
            half8 A1 = *(const half8*)(wp + ((size_t)((tap*2+kt)*8 + wave*2 + 1)*64 + lane)*8);
#pragma unroll
            for (int pt = 0; pt < 2; ++pt) {
                half8 B = *(const half8*)(buf + (pt*16 + r15)*72 + kt*32 + q4*8);
                acc[0][pt] = __builtin_amdgcn_mfma_f32_16x16x32_f16(A0, B, acc[0][pt], 0, 0, 0);
                acc[1][pt] = __builtin_amdgcn_mfma_f32_16x16x32_f16(A1, B, acc[1][pt], 0, 0, 0);
            }
        }
    };

    // prologue
    loadMetaN(0);
#pragma unroll
    for (int j = 0; j < 4; ++j) { MOc[j] = MOn[j]; MWc[j] = MWn[j]; }
    issue(0);
    loadMetaN(4);
    commit(0, cols[0]);
    __syncthreads();

    for (int r = 0; r < R; ++r) {
        const bool more = (r + 1 < R);
        if (more) {
#pragma unroll
            for (int j = 0; j < 4; ++j) { MOc[j] = MOn[j]; MWc[j] = MWn[j]; }
            issue(4*r + 4);
            loadMetaN(4*r + 8);
        }
#pragma unroll
        for (int tt = 0; tt < 4; ++tt) gemm(4*r + tt, cols[r&1][tt]);
        if (more) commit(4*r + 4, cols[(r+1)&1]);
        __syncthreads();
    }

    // epilogue: D row=(lane>>4)*4+reg (oc), col=lane&15 (px)
#pragma unroll
    for (int i = 0; i < 2; ++i)
#pragma unroll
    for (int pt = 0; pt < 2; ++pt)
#pragma unroll
    for (int reg = 0; reg < 4; ++reg) {
        const int oc = (wave*2 + i)*16 + q4*4 + reg;
        const int p2 = pix0 + pt*16 + r15;
        float v = fmaxf(acc[i][pt][reg] + bias[oc], 0.f);
        out[((size_t)b*256 + outc0 + oc)*3136 + p2] = v;
    }
}

// ---------------- launch ----------------
extern "C" void kernel_launch(void* const* d_in, const int* in_sizes, int n_in,
                              void* d_out, int out_size, void* d_ws, size_t ws_size,
                              hipStream_t stream)
{
    (void)in_sizes; (void)n_in; (void)out_size; (void)ws_size;
    const float* x     = (const float*)d_in[0];
    const float* w3    = (const float*)d_in[1];
    const float* b3    = (const float*)d_in[2];
    const float* off3w = (const float*)d_in[3];
    const float* off3b = (const float*)d_in[4];
    const float* w5    = (const float*)d_in[5];
    const float* b5    = (const float*)d_in[6];
    const float* off5w = (const float*)d_in[7];
    const float* off5b = (const float*)d_in[8];
    const float* subw  = (const float*)d_in[9];
    const float* subb  = (const float*)d_in[10];

    unsigned short* us = (unsigned short*)d_ws;
    float* fb   = (float*)((char*)d_ws + FB_BYTES);
    int4*  offs = (int4*)(fb + F_OFFS);
    uint2* wts  = (uint2*)(fb + F_WTS);
    float* out  = (float*)d_out;

    // pad/transpose x (incl. border zero) + weight packing — no memset needed
    xpose<<<dim3(50, 8), dim3(256), 0, stream>>>(x, us + US_XP);
    prep_w<<<dim3(512), dim3(256), 0, stream>>>(
        w3, b3, off3w, off3b, w5, b5, off5w, off5b, subw, subb, us, fb);

    // offset conv + fused bilinear-meta epilogue -> offs/wts
    convo6<<<dim3(98, 8), dim3(256), 0, stream>>>(
        us + US_XP, us + US_WOFF, fb + F_BOM, offs, wts);

    // deform convs + fused sub tap + bias + relu; z=0 k5 first, z=1 k3 packs tail
    convd6<<<dim3(98, 8, 2), dim3(256), 0, stream>>>(
        us + US_XP, offs, wts, out,
        us + US_W5, fb + F_B5, us + US_W3, fb + F_B3);
}

// Round 11
// 153.622 us; speedup vs baseline: 1.9706x; 1.9706x over previous
//
#include <hip/hip_runtime.h>
#include <math.h>

typedef _Float16 half8 __attribute__((ext_vector_type(8)));
typedef _Float16 half2v __attribute__((ext_vector_type(2)));
typedef __attribute__((ext_vector_type(4))) float f32x4;

// ---------------- workspace layout ----------------
#define US_XP    0
#define N_XP     (8*60*60*64)            // padded NHWC x, pad=2, fp16
#define US_WOFF  (US_XP + N_XP)          // offset-conv weights, 26 taps (tap25 = 0 pad)
#define N_WOFF   (26*2*8*64*8)
#define US_W5    (US_WOFF + N_WOFF)      // w5 (25) + sub tap = 26
#define N_W5     (26*2*8*64*8)
#define US_W3    (US_W5 + N_W5)          // w3 (9) + sub tap = 10
#define N_W3     (10*2*8*64*8)
#define US_TOT   (US_W3 + N_W3)
#define FB_BYTES (((US_TOT*2) + 15) & ~15)
#define F_BOM    0                       // offset-conv bias (128, padded)
#define F_B5     128                     // b5 + sub_b
#define F_B3     256                     // b3 + sub_b
#define N_ITEMS  (8*34*3136)             // bilinear meta items (25 k5 + 9 k3)
#define F_OFFS   384                     // int4 per item (corner byte offsets)
#define F_WTS    (F_OFFS + N_ITEMS*4)    // uint2 per item (4 fp16 weights)

__device__ __forceinline__ unsigned short f2h(float f) {
    union { _Float16 h; unsigned short s; } c; c.h = (_Float16)f; return c.s;
}
__device__ __forceinline__ half2v splat_lo(unsigned u) {
    union { unsigned short s; _Float16 h; } c; c.s = (unsigned short)(u & 0xffffu);
    return (half2v){c.h, c.h};
}
__device__ __forceinline__ half2v splat_hi(unsigned u) {
    union { unsigned short s; _Float16 h; } c; c.s = (unsigned short)(u >> 16);
    return (half2v){c.h, c.h};
}
__device__ __forceinline__ unsigned blendh(unsigned a, unsigned b, unsigned c, unsigned d,
                                           half2v W00, half2v W01, half2v W10, half2v W11) {
    union { unsigned u; half2v h; } A, B, C, D, R;
    A.u = a; B.u = b; C.u = c; D.u = d;
    R.h = A.h*W00 + B.h*W01 + C.h*W10 + D.h*W11;   // v_pk_mul/fma_f16
    return R.u;
}

// ---------------- xpose: x NCHW fp32 -> padded NHWC fp16 + border zero ----------------
__global__ __launch_bounds__(256) void xpose(const float* __restrict__ x,
                                             unsigned short* __restrict__ xp)
{
    const int b = blockIdx.y;
    if (blockIdx.x == 49) {              // border zeroing (464 px per batch)
        const uint4 z = make_uint4(0,0,0,0);
        for (int i = threadIdx.x; i < 464*8; i += 256) {
            const int px = i >> 3, part = i & 7;
            int oy, ox;
            if (px < 120)      { oy = px/60;            ox = px%60; }
            else if (px < 240) { int j = px-120; oy = 58 + j/60; ox = j%60; }
            else               { int j = px-240; oy = 2 + (j>>2); ox = ((j&2)?58:0) + (j&1); }
            *(uint4*)(xp + ((size_t)b*3600 + oy*60 + ox)*64 + part*8) = z;
        }
        return;
    }
    __shared__ float ld[64*65];
    const int px0 = blockIdx.x * 64;
    const int t   = threadIdx.x;
#pragma unroll
    for (int c0 = 0; c0 < 64; c0 += 4) {
        const int c = c0 + (t >> 6);
        const int p = t & 63;
        ld[c*65 + p] = x[((size_t)(b*64 + c))*3136 + px0 + p];
    }
    __syncthreads();
    const int lp = t >> 2;
    const int ch0 = (t & 3) * 16;
    const int px = px0 + lp;
    const int oy = px/56, ox = px - oy*56;
    unsigned short* dst = xp + ((size_t)b*3600 + (oy+2)*60 + (ox+2))*64 + ch0;
    unsigned short tmp[16];
#pragma unroll
    for (int k = 0; k < 16; ++k) tmp[k] = f2h(ld[(ch0 + k)*65 + lp]);
    *(uint4*)dst       = *(uint4*)&tmp[0];
    *(uint4*)(dst + 8) = *(uint4*)&tmp[8];
}

// ---------------- prep_w: pack weights into A-frag order + biases (fp16) ----------------
// A-frag (16x16x32): lane l holds A[oc=l&15][c=(l>>4)*8+j]. idx ((((tap*2+kt)*8+oct)*64+lane)*8+j)
__global__ __launch_bounds__(256) void prep_w(
    const float* __restrict__ w3, const float* __restrict__ b3,
    const float* __restrict__ off3w, const float* __restrict__ off3b,
    const float* __restrict__ w5, const float* __restrict__ b5,
    const float* __restrict__ off5w, const float* __restrict__ off5b,
    const float* __restrict__ subw, const float* __restrict__ subb,
    unsigned short* __restrict__ us, float* __restrict__ fb)
{
    const int NTOT = US_TOT + 384;
    for (int i = US_WOFF + blockIdx.x*256 + threadIdx.x; i < NTOT; i += gridDim.x*256) {
        if (i < US_TOT) {
            float v = 0.f;
            int j, mode;
            if (i < US_W5)      { j = i - US_WOFF; mode = 0; }
            else if (i < US_W3) { j = i - US_W5;   mode = 1; }
            else                { j = i - US_W3;   mode = 2; }
            int j8   = j & 7;
            int lane = (j >> 3) & 63;
            int oct  = (j >> 9) & 7;
            int kt   = (j >> 12) & 1;
            int tap  = j >> 13;
            int oc   = oct*16 + (lane & 15);
            int c    = kt*32 + (lane >> 4)*8 + j8;
            if (mode == 0) {                    // offset conv (5x5, k3 embedded; tap25 = 0)
                if (oc < 27 && tap < 25) {
                    int ky = tap/5, kx = tap%5;
                    if (ky>=1 && ky<=3 && kx>=1 && kx<=3)
                        v = off3w[((oc*64 + c)*3 + (ky-1))*3 + (kx-1)];
                } else if (oc >= 27 && oc < 102 && tap < 25) {
                    v = off5w[((oc-27)*64 + c)*25 + tap];
                }
            } else if (mode == 1) {             // w5 (25) + sub tap
                v = (tap < 25) ? w5[(oc*64 + c)*25 + tap] : subw[oc*64 + c];
            } else {                            // w3 (9) + sub tap
                v = (tap < 9) ? w3[(oc*64 + c)*9 + tap] : subw[oc*64 + c];
            }
            us[i] = f2h(v);
        } else {
            int fj = i - US_TOT;
            float v;
            if (fj < 128)      v = (fj < 27) ? off3b[fj] : ((fj < 102) ? off5b[fj-27] : 0.f);
            else if (fj < 256) { int o = fj-128; v = b5[o] + subb[o]; }
            else               { int o = fj-256; v = b3[o] + subb[o]; }
            fb[fj] = v;
        }
    }
}

// ---------------- offset conv: 32 px x 128 oc, 2 taps/round, fused meta epilogue ----------------
// (R9-passing convo3 structure, fp16 fragments)
__global__ __launch_bounds__(256, 6) void convo7(
    const unsigned short* __restrict__ xp,
    const unsigned short* __restrict__ wp, const float* __restrict__ bias,
    int4* __restrict__ offs, uint2* __restrict__ wts)
{
    const int b    = blockIdx.y;
    const int pix0 = blockIdx.x * 32;
    const int lane = threadIdx.x & 63;
    const int wave = threadIdx.x >> 6;
    const int r15 = lane & 15, q4 = lane >> 4;
    const int cg  = lane & 7,  pr = lane >> 3;

    __shared__ __align__(16) unsigned short cols[2][2][32*72];   // 18432 B

    f32x4 acc[2][2] = {{{0.f,0.f,0.f,0.f},{0.f,0.f,0.f,0.f}},
                       {{0.f,0.f,0.f,0.f},{0.f,0.f,0.f,0.f}}};

    const char* xb = (const char*)(xp + (size_t)b*(60*60*64));
    const int px  = wave*8 + pr;
    const int pix = pix0 + px;
    const int oy  = pix/56, ox = pix - oy*56;
    const int coff = (((oy+2)*60) + ox + 2) << 7;

    uint4 G0, G1;
    auto issue = [&](int ta, int tb) {
        int ka = 0, kb = 0;
        if (ta < 25) { int ky = ta/5, kx = ta - ky*5; ka = ((ky-2)*60 + (kx-2)) << 7; }
        if (tb < 25) { int ky = tb/5, kx = tb - ky*5; kb = ((ky-2)*60 + (kx-2)) << 7; }
        G0 = *(const uint4*)(xb + coff + ka + cg*16);
        G1 = *(const uint4*)(xb + coff + kb + cg*16);
    };
    auto commit = [&](unsigned short* bufa, unsigned short* bufb) {
        *(uint4*)&bufa[px*72 + cg*8] = G0;
        *(uint4*)&bufb[px*72 + cg*8] = G1;
    };
    auto gemm = [&](int tap, const unsigned short* buf) {
#pragma unroll
        for (int kt = 0; kt < 2; ++kt) {
            half8 A0 = *(const half8*)(wp + ((size_t)((tap*2+kt)*8 + wave*2    )*64 + lane)*8);
            half8 A1 = *(const half8*)(wp + ((size_t)((tap*2+kt)*8 + wave*2 + 1)*64 + lane)*8);
#pragma unroll
            for (int pt = 0; pt < 2; ++pt) {
                half8 Bf = *(const half8*)(buf + (pt*16 + r15)*72 + kt*32 + q4*8);
                acc[0][pt] = __builtin_amdgcn_mfma_f32_16x16x32_f16(A0, Bf, acc[0][pt], 0, 0, 0);
                acc[1][pt] = __builtin_amdgcn_mfma_f32_16x16x32_f16(A1, Bf, acc[1][pt], 0, 0, 0);
            }
        }
    };

    issue(0, 1);
    commit(cols[0][0], cols[0][1]);
    __syncthreads();
    for (int r = 0; r < 13; ++r) {
        if (r + 1 < 13) issue(2*r+2, 2*r+3);
        gemm(2*r,   cols[r&1][0]);
        gemm(2*r+1, cols[r&1][1]);
        if (r + 1 < 13) commit(cols[(r+1)&1][0], cols[(r+1)&1][1]);
        __syncthreads();
    }

    // ---- epilogue: om tile -> LDS (fp32 128x32 = 16 KB), then bilinear meta ----
    float* omt = (float*)cols;
#pragma unroll
    for (int i = 0; i < 2; ++i)
#pragma unroll
    for (int pt = 0; pt < 2; ++pt)
#pragma unroll
    for (int reg = 0; reg < 4; ++reg) {
        const int oc = (wave*2 + i)*16 + q4*4 + reg;
        const int p2 = pt*16 + r15;
        omt[oc*32 + p2] = acc[i][pt][reg] + bias[oc];
    }
    __syncthreads();

    const int tid = threadIdx.x;
#pragma unroll
    for (int itr = 0; itr < 5; ++itr) {
        const int idx = itr*256 + tid;
        if (idx >= 34*32) break;
        const int t  = idx >> 5;
        const int p2 = idx & 31;
        const int pix2 = pix0 + p2;
        const int oy2 = pix2/56, ox2 = pix2 - oy2*56;
        int ky, kx, cdy, cdx, cml, HP, SH;
        if (t < 25) { ky = t/5; kx = t%5; cdy = 27+t; cdx = 52+t; cml = 77+t; HP = 60; SH = 0; }
        else { int tt = t-25; ky = tt/3; kx = tt%3; cdy = tt; cdx = 9+tt; cml = 18+tt; HP = 58; SH = 1; }
        const float dy = omt[cdy*32 + p2];
        const float dx = omt[cdx*32 + p2];
        const float ml = omt[cml*32 + p2];
        const float mask = 1.f / (1.f + __expf(-ml));
        const float py = (float)(oy2 + ky) + dy;
        const float qx = (float)(ox2 + kx) + dx;
        const float y0f = floorf(py), x0f = floorf(qx);
        const float ty = py - y0f, tx = qx - x0f;
        const int y0 = (int)y0f, x0 = (int)x0f, y1 = y0+1, x1 = x0+1;
        float w00 = (1.f-ty)*(1.f-tx)*mask;
        float w01 = (1.f-ty)*tx*mask;
        float w10 = ty*(1.f-tx)*mask;
        float w11 = ty*tx*mask;
        const bool vy0 = (unsigned)y0 < (unsigned)HP, vy1 = (unsigned)y1 < (unsigned)HP;
        const bool vx0 = (unsigned)x0 < (unsigned)HP, vx1 = (unsigned)x1 < (unsigned)HP;
        if (!(vy0 && vx0)) w00 = 0.f;
        if (!(vy0 && vx1)) w01 = 0.f;
        if (!(vy1 && vx0)) w10 = 0.f;
        if (!(vy1 && vx1)) w11 = 0.f;
        const int yc0 = min(max(y0,0),HP-1)+SH, yc1 = min(max(y1,0),HP-1)+SH;
        const int xc0 = min(max(x0,0),HP-1)+SH, xc1 = min(max(x1,0),HP-1)+SH;
        const int mi = (b*34 + t)*3136 + pix2;
        offs[mi] = make_int4((yc0*60+xc0)<<7, (yc0*60+xc1)<<7, (yc1*60+xc0)<<7, (yc1*60+xc1)<<7);
        wts[mi]  = make_uint2((unsigned)f2h(w00) | ((unsigned)f2h(w01) << 16),
                              (unsigned)f2h(w10) | ((unsigned)f2h(w11) << 16));
    }
}

// ---------------- deform conv: 32px x 128oc, 2 taps/round, pk_fma_f16 blend ----------
// (R9-passing convd5 structure, fp16 fragments + packed blend)
__global__ __launch_bounds__(256, 3) void convd7(
    const unsigned short* __restrict__ xp,
    const int4* __restrict__ offs, const uint2* __restrict__ wts,
    float* __restrict__ out,
    const unsigned short* __restrict__ wp5, const float* __restrict__ bias5,
    const unsigned short* __restrict__ wp3, const float* __restrict__ bias3)
{
    const int kind = blockIdx.z;                  // 0: k5 (first), 1: k3
    const unsigned short* wp = kind ? wp3 : wp5;
    const float* bias = kind ? bias3 : bias5;
    const int R     = kind ? 5  : 13;
    const int K2    = kind ? 9  : 25;
    const int tofs  = kind ? 25 : 0;
    const int outc0 = kind ? 0  : 128;

    const int b    = blockIdx.y;
    const int pix0 = blockIdx.x * 32;
    const int lane = threadIdx.x & 63;
    const int wave = threadIdx.x >> 6;
    const int r15 = lane & 15, q4 = lane >> 4;
    const int cg  = lane & 7,  pr = lane >> 3;

    __shared__ __align__(16) unsigned short cols[2][2][32*72];   // 18432 B

    f32x4 acc[2][2] = {{{0.f,0.f,0.f,0.f},{0.f,0.f,0.f,0.f}},
                       {{0.f,0.f,0.f,0.f},{0.f,0.f,0.f,0.f}}};

    const char* xb = (const char*)(xp + (size_t)b*(60*60*64));
    const int px  = wave*8 + pr;
    const int pix = pix0 + px;
    const int oy  = pix/56, ox = pix - oy*56;
    const int coff  = (((oy+2)*60) + ox + 2) << 7;
    const int mbase = (b*34 + tofs)*3136 + pix;

    uint4 C0[4], C1[4];
    uint2 WC0, WC1;
    int4  MOc0, MOc1, MOn0, MOn1;
    uint2 MWc0, MWc1, MWn0, MWn1;

    auto loadMetaN = [&](int ta, int tb) {
        const int a  = min(ta, K2-1) * 3136;
        const int bb = min(tb, K2-1) * 3136;
        MOn0 = offs[mbase + a];  MWn0 = wts[mbase + a];
        MOn1 = offs[mbase + bb]; MWn1 = wts[mbase + bb];
    };
    auto issue = [&](int ta, int tb) {
        if (ta >= K2) {
            C0[0] = *(const uint4*)(xb + coff + cg*16);
        } else {
            WC0 = MWc0;
            C0[0] = *(const uint4*)(xb + MOc0.x + cg*16);
            C0[1] = *(const uint4*)(xb + MOc0.y + cg*16);
            C0[2] = *(const uint4*)(xb + MOc0.z + cg*16);
            C0[3] = *(const uint4*)(xb + MOc0.w + cg*16);
        }
        if (tb >= K2) {
            C1[0] = *(const uint4*)(xb + coff + cg*16);
        } else {
            WC1 = MWc1;
            C1[0] = *(const uint4*)(xb + MOc1.x + cg*16);
            C1[1] = *(const uint4*)(xb + MOc1.y + cg*16);
            C1[2] = *(const uint4*)(xb + MOc1.z + cg*16);
            C1[3] = *(const uint4*)(xb + MOc1.w + cg*16);
        }
    };
    auto commit = [&](int ta, int tb, unsigned short* ba, unsigned short* bb) {
        uint4 res;
        if (ta >= K2) {
            res = C0[0];
        } else {
            const half2v W00 = splat_lo(WC0.x), W01 = splat_hi(WC0.x);
            const half2v W10 = splat_lo(WC0.y), W11 = splat_hi(WC0.y);
            res.x = blendh(C0[0].x, C0[1].x, C0[2].x, C0[3].x, W00, W01, W10, W11);
            res.y = blendh(C0[0].y, C0[1].y, C0[2].y, C0[3].y, W00, W01, W10, W11);
            res.z = blendh(C0[0].z, C0[1].z, C0[2].z, C0[3].z, W00, W01, W10, W11);
            res.w = blendh(C0[0].w, C0[1].w, C0[2].w, C0[3].w, W00, W01, W10, W11);
        }
        *(uint4*)&ba[px*72 + cg*8] = res;
        if (tb >= K2) {
            res = C1[0];
        } else {
            const half2v W00 = splat_lo(WC1.x), W01 = splat_hi(WC1.x);
            const half2v W10 = splat_lo(WC1.y), W11 = splat_hi(WC1.y);
            res.x = blendh(C1[0].x, C1[1].x, C1[2].x, C1[3].x, W00, W01, W10, W11);
            res.y = blendh(C1[0].y, C1[1].y, C1[2].y, C1[3].y, W00, W01, W10, W11);
            res.z = blendh(C1[0].z, C1[1].z, C1[2].z, C1[3].z, W00, W01, W10, W11);
            res.w = blendh(C1[0].w, C1[1].w, C1[2].w, C1[3].w, W00, W01, W10, W11);
        }
        *(uint4*)&bb[px*72 + cg*8] = res;
    };
    auto gemm = [&](int tap, const unsigned short* buf) {
#pragma unroll
        for (int kt = 0; kt < 2; ++kt) {
            half8 A0 = *(const half8*)(wp + ((size_t)((tap*2+kt)*8 + wave*2    )*64 + lane)*8);
            half8 A1 = *(const half8*)(wp + ((size_t)((tap*2+kt)*8 + wave*2 + 1)*64 + lane)*8);
#pragma unroll
            for (int pt = 0; pt < 2; ++pt) {
                half8 B = *(const half8*)(buf + (pt*16 + r15)*72 + kt*32 + q4*8);
                acc[0][pt] = __builtin_amdgcn_mfma_f32_16x16x32_f16(A0, B, acc[0][pt], 0, 0, 0);
                acc[1][pt] = __builtin_amdgcn_mfma_f32_16x16x32_f16(A1, B, acc[1][pt], 0, 0, 0);
            }
        }
    };

    // prologue
    loadMetaN(0, 1);
    MOc0 = MOn0; MWc0 = MWn0; MOc1 = MOn1; MWc1 = MWn1;
    issue(0, 1);
    loadMetaN(2, 3);
    commit(0, 1, cols[0][0], cols[0][1]);
    __syncthreads();

    for (int r = 0; r < R; ++r) {
        const bool more = (r + 1 < R);
        if (more) {
            MOc0 = MOn0; MWc0 = MWn0; MOc1 = MOn1; MWc1 = MWn1;
            issue(2*r+2, 2*r+3);           // corners for next round
            loadMetaN(2*r+4, 2*r+5);       // meta for round r+2
        }
        gemm(2*r,   cols[r&1][0]);
        gemm(2*r+1, cols[r&1][1]);
        if (more) commit(2*r+2, 2*r+3, cols[(r+1)&1][0], cols[(r+1)&1][1]);
        __syncthreads();
    }

    // epilogue: D row=(lane>>4)*4+reg (oc), col=lane&15 (px)
#pragma unroll
    for (int i = 0; i < 2; ++i)
#pragma unroll
    for (int pt = 0; pt < 2; ++pt)
#pragma unroll
    for (int reg = 0; reg < 4; ++reg) {
        const int oc = (wave*2 + i)*16 + q4*4 + reg;
        const int p2 = pix0 + pt*16 + r15;
        float v = fmaxf(acc[i][pt][reg] + bias[oc], 0.f);
        out[((size_t)b*256 + outc0 + oc)*3136 + p2] = v;
    }
}

// ---------------- launch ----------------
extern "C" void kernel_launch(void* const* d_in, const int* in_sizes, int n_in,
                              void* d_out, int out_size, void* d_ws, size_t ws_size,
                              hipStream_t stream)
{
    (void)in_sizes; (void)n_in; (void)out_size; (void)ws_size;
    const float* x     = (const float*)d_in[0];
    const float* w3    = (const float*)d_in[1];
    const float* b3    = (const float*)d_in[2];
    const float* off3w = (const float*)d_in[3];
    const float* off3b = (const float*)d_in[4];
    const float* w5    = (const float*)d_in[5];
    const float* b5    = (const float*)d_in[6];
    const float* off5w = (const float*)d_in[7];
    const float* off5b = (const float*)d_in[8];
    const float* subw  = (const float*)d_in[9];
    const float* subb  = (const float*)d_in[10];

    unsigned short* us = (unsigned short*)d_ws;
    float* fb   = (float*)((char*)d_ws + FB_BYTES);
    int4*  offs = (int4*)(fb + F_OFFS);
    uint2* wts  = (uint2*)(fb + F_WTS);
    float* out  = (float*)d_out;

    // pad/transpose x (incl. border zero) + weight packing
    xpose<<<dim3(50, 8), dim3(256), 0, stream>>>(x, us + US_XP);
    prep_w<<<dim3(512), dim3(256), 0, stream>>>(
        w3, b3, off3w, off3b, w5, b5, off5w, off5b, subw, subb, us, fb);

    // offset conv + fused bilinear-meta epilogue -> offs/wts
    convo7<<<dim3(98, 8), dim3(256), 0, stream>>>(
        us + US_XP, us + US_WOFF, fb + F_BOM, offs, wts);

    // deform convs + fused sub tap + bias + relu; z=0 k5 first, z=1 k3 packs tail
    convd7<<<dim3(98, 8, 2), dim3(256), 0, stream>>>(
        us + US_XP, offs, wts, out,
        us + US_W5, fb + F_B5, us + US_W3, fb + F_B3);
}